// Round 4
// baseline (632.528 us; speedup 1.0000x reference)
//
#include <hip/hip_runtime.h>
#include <hip/hip_bf16.h>
#include <math.h>

// Problem constants
#define LL 512
#define BB 8
#define NN 32
#define DD 256
#define GH 128
#define AH 64

#define PA 520     // sA pitch: [32 rows][512 k] bf16; row step 1040B -> 2-way bank alias (free)
#define NPAIR 4    // (l,b) pairs per block
#define NBLK (LL * BB / NPAIR)   // 1024 = 256 CU x 4 resident -> fully persistent

typedef short short8 __attribute__((ext_vector_type(8)));   // 8 bf16 = 4 VGPRs (MFMA A/B frag)
typedef float f32x4  __attribute__((ext_vector_type(4)));   // MFMA C/D frag

__device__ __forceinline__ float bf2f(unsigned short u) {
  return __uint_as_float(((unsigned int)u) << 16);
}
__device__ __forceinline__ unsigned short f2bf(float f) {
  union { __hip_bfloat16 h; unsigned short u; } cv;
  cv.h = __float2bfloat16(f);
  return cv.u;
}

// Barrier that orders LDS only: does NOT drain vmcnt, so in-flight global
// prefetch loads (register destinations, dependency-tracked) float across.
// All cross-wave communication in this kernel is through LDS, and no global
// store is ever re-read in-kernel, so lgkmcnt(0) is sufficient.
__device__ __forceinline__ void barrier_lds() {
  asm volatile("s_waitcnt lgkmcnt(0)" ::: "memory");
  __builtin_amdgcn_s_barrier();
  __builtin_amdgcn_sched_barrier(0);
}

// ---------------------------------------------------------------------------
// Pre-pass: gw1/aw1 fp32 -> bf16, tiled [k/32][j][32] so a wave's MFMA
// B-fragment load (lane (lr,lg) -> j=jt*16+lr, k=kb*32+lg*8) is one fully
// coalesced contiguous 1KB global_load_dwordx4 per fragment.
//   gw1t: ws[0      .. 65535] = gw1t[kb<16][j<128][ko<32]
//   aw1t: ws[65536 .. 81919]  = aw1t[kb< 8][j< 64][ko<32]
// ---------------------------------------------------------------------------
extern "C" __global__ void wconv(const float* __restrict__ gw1,
                                 const float* __restrict__ aw1,
                                 unsigned short* __restrict__ ws)
{
  int o = blockIdx.x * 256 + threadIdx.x;     // grid = 320*256 = 81920 exactly
  if (o < 65536) {
    int kb = o >> 12, r = o & 4095, j = r >> 5, ko = r & 31;
    ws[o] = f2bf(gw1[j * 512 + kb * 32 + ko]);
  } else {
    int o2 = o - 65536;
    int kb = o2 >> 11, j = (o2 >> 5) & 63, ko = o2 & 31;
    ws[o] = f2bf(aw1[j * 256 + kb * 32 + ko]);
  }
}

extern "C" __global__ __launch_bounds__(256, 4)
void dynfusion_kernel(const float* __restrict__ vert,
                      const float* __restrict__ horiz,
                      const int*   __restrict__ mask,   // [B][N][L] bool as int32
                      const float* __restrict__ gb1,    // [128]
                      const float* __restrict__ gw2,    // [1][128]
                      const float* __restrict__ gb2,    // [1]
                      const float* __restrict__ ab1,    // [64]
                      const float* __restrict__ aw2,    // [1][64]
                      const float* __restrict__ ab2,    // [1]
                      const unsigned short* __restrict__ ws,  // bf16 tiled weights
                      float* __restrict__ out)
{
  __shared__ __align__(16) unsigned short sA[NN * PA];   // 33,280 B (comb; pm overwrites k<256)
  __shared__ float sPart[NN][2];
  __shared__ float sGb1R[GH], sGw2R[GH];
  __shared__ float sAb1R[AH], sAw2R[AH];
  __shared__ float sGate[NN], sAttn[NN], sScal[2];

  const int t   = threadIdx.x;
  const int bid = blockIdx.x;

  const int lane = t & 63;
  const int w    = t >> 6;              // wave id 0..3
  const int lr   = lane & 15;           // row(A) / col(B,C) within 16-tile
  const int lg   = lane >> 4;           // k-group (8 consecutive k) / C row-group
  const int mt   = w & 1;               // M-tile (message group of 16)
  const int ns   = (w >> 1) << 6;       // GEMM1 j-strip base: 0 or 64
  const int js   = (w >> 1) << 5;       // GEMM2 j-strip base: 0 or 32
  const int aoff = (mt * 16 + lr) * PA; // A-frag row offset in sA

  const unsigned short* __restrict__ gw1t = ws;           // [16][128][32]
  const unsigned short* __restrict__ aw1t = ws + 65536;   // [8][64][32]

  float* __restrict__ outF  = out;                 // fused  [L,B,D]
  float* __restrict__ outPM = out + 1048576;       // per_msg[L,B,N,D]
  float* __restrict__ outAT = out + 34603008;      // attn   [B,L,N]

  // ---- once: small vectors ----
  if (t < GH) { sGb1R[t] = gb1[t]; sGw2R[t] = gw2[t]; }
  if (t < AH) { sAb1R[t] = ab1[t]; sAw2R[t] = aw2[t]; }
  if (t == 0) { sScal[0] = gb2[0]; sScal[1] = ab2[0]; }

  // ---- prologue: prefetch pair 0 inputs into registers ----
  float4 pf[16];
  {
    const size_t base0 = (size_t)(bid * NPAIR) * NN * DD;
#pragma unroll
    for (int i = 0; i < 16; ++i) {
      int idx4 = i * 256 + t;             // 4096 float4 = 32 rows x 128 quads
      int n  = idx4 >> 7;
      int c4 = (idx4 & 127) << 2;         // wave-uniform vert/horiz split
      const float* src = (c4 < DD) ? (vert  + base0 + n * DD + c4)
                                   : (horiz + base0 + n * DD + (c4 - DD));
      pf[i] = *reinterpret_cast<const float4*>(src);
    }
  }
  int mval = 0;
  {
    int lb0 = bid * NPAIR;
    if (t < NN) mval = mask[((size_t)(lb0 & 7) * NN + t) * LL + (lb0 >> 3)];
  }

#pragma unroll 1
  for (int p = 0; p < NPAIR; ++p) {
    const int lb = bid * NPAIR + p;
    const int l  = lb >> 3;
    const int b  = lb & 7;
    const size_t msgBase = (size_t)lb * NN * DD;

    // Loop-top barrier: previous pair's P5 reads of sA done. Full
    // __syncthreads() here is ~free (pf[] is consumed immediately after,
    // so the compiler would insert the vmcnt wait in P0 anyway) and keeps
    // the store queue bounded across pair iterations.
    __syncthreads();

    // ---------------- P0: registers -> sA (bf16 row-major) ----------------
#pragma unroll
    for (int i = 0; i < 16; ++i) {
      int idx4 = i * 256 + t;
      int n  = idx4 >> 7;
      int c4 = (idx4 & 127) << 2;
      ushort4 pk;
      pk.x = f2bf(pf[i].x); pk.y = f2bf(pf[i].y);
      pk.z = f2bf(pf[i].z); pk.w = f2bf(pf[i].w);
      *reinterpret_cast<ushort4*>(&sA[n * PA + c4]) = pk;
    }

    // ---- issue next-pair prefetch (floats across all lgkm-barriers below) ----
    int mnext = 0;
    if (p + 1 < NPAIR) {
      const size_t baseN = msgBase + (size_t)NN * DD;
#pragma unroll
      for (int i = 0; i < 16; ++i) {
        int idx4 = i * 256 + t;
        int n  = idx4 >> 7;
        int c4 = (idx4 & 127) << 2;
        const float* src = (c4 < DD) ? (vert  + baseN + n * DD + c4)
                                     : (horiz + baseN + n * DD + (c4 - DD));
        pf[i] = *reinterpret_cast<const float4*>(src);
      }
      int lb2 = lb + 1;
      if (t < NN) mnext = mask[((size_t)(lb2 & 7) * NN + t) * LL + (lb2 >> 3)];
    }

    barrier_lds();                        // sA ready (LDS-only; prefetch stays in flight)

    // ---------------- P1: gate GEMM h[32][128] = comb[32][512] @ gw1^T ----------------
    f32x4 acc1[4] = {};
    {
      const unsigned short* bgp = gw1t + (ns + lr) * 32 + lg * 8;  // + ks*4096 + nt*512
      __builtin_amdgcn_s_setprio(1);
#pragma unroll
      for (int ks = 0; ks < 16; ++ks) {
        short8 af = *reinterpret_cast<const short8*>(&sA[aoff + ks * 32 + lg * 8]);
#pragma unroll
        for (int nt = 0; nt < 4; ++nt) {
          short8 bf = *reinterpret_cast<const short8*>(bgp + ks * 4096 + nt * 512);
          acc1[nt] = __builtin_amdgcn_mfma_f32_16x16x32_bf16(af, bf, acc1[nt], 0, 0, 0);
        }
      }
      __builtin_amdgcn_s_setprio(0);
    }

    // gate epilogue: relu(h+gb1) . gw2 ; lane holds rows mt*16+lg*4+r, col j=ns+nt*16+lr
    {
      float pr[4] = {0.f, 0.f, 0.f, 0.f};
#pragma unroll
      for (int nt = 0; nt < 4; ++nt) {
        int j = ns + nt * 16 + lr;
        float bj = sGb1R[j], wj = sGw2R[j];
#pragma unroll
        for (int r = 0; r < 4; ++r) {
          float hv = fmaxf(acc1[nt][r] + bj, 0.0f);
          pr[r] += hv * wj;
        }
      }
#pragma unroll
      for (int msk = 1; msk <= 8; msk <<= 1)
#pragma unroll
        for (int r = 0; r < 4; ++r) pr[r] += __shfl_xor(pr[r], msk);
      if (lr == 0) {
#pragma unroll
        for (int r = 0; r < 4; ++r) sPart[mt * 16 + lg * 4 + r][w >> 1] = pr[r];
      }
    }
    barrier_lds();
    if (t < NN) {
      float sv = sScal[0] + sPart[t][0] + sPart[t][1];
      sGate[t] = 1.0f / (1.0f + __expf(-sv));
    }
    barrier_lds();

    // ---------------- P2: per_msg = gate*vert + (1-gate)*horiz ----------------
#pragma unroll
    for (int i = 0; i < 8; ++i) {
      int idx4 = i * 256 + t;               // 2048 = 32 n x 64 quads
      int n  = idx4 >> 6;
      int d0 = (idx4 & 63) << 2;
      float g = sGate[n];
      ushort4 vq = *reinterpret_cast<const ushort4*>(&sA[n * PA + d0]);
      ushort4 hq = *reinterpret_cast<const ushort4*>(&sA[n * PA + DD + d0]);
      float4 prv;
      prv.x = bf2f(hq.x) + g * (bf2f(vq.x) - bf2f(hq.x));
      prv.y = bf2f(hq.y) + g * (bf2f(vq.y) - bf2f(hq.y));
      prv.z = bf2f(hq.z) + g * (bf2f(vq.z) - bf2f(hq.z));
      prv.w = bf2f(hq.w) + g * (bf2f(vq.w) - bf2f(hq.w));
      ushort4 pq;
      pq.x = f2bf(prv.x); pq.y = f2bf(prv.y); pq.z = f2bf(prv.z); pq.w = f2bf(prv.w);
      *reinterpret_cast<ushort4*>(&sA[n * PA + d0]) = pq;
      *reinterpret_cast<float4*>(outPM + msgBase + n * DD + d0) = prv;
    }
    barrier_lds();

    // ---------------- P3: scorer GEMM a[32][64] = pm[32][256] @ aw1^T ----------------
    f32x4 acc2[2] = {};
    {
      const unsigned short* bap = aw1t + (js + lr) * 32 + lg * 8;  // + ks*2048 + q*512
      __builtin_amdgcn_s_setprio(1);
#pragma unroll
      for (int ks = 0; ks < 8; ++ks) {
        short8 af = *reinterpret_cast<const short8*>(&sA[aoff + ks * 32 + lg * 8]);
#pragma unroll
        for (int q = 0; q < 2; ++q) {
          short8 bf = *reinterpret_cast<const short8*>(bap + ks * 2048 + q * 512);
          acc2[q] = __builtin_amdgcn_mfma_f32_16x16x32_bf16(af, bf, acc2[q], 0, 0, 0);
        }
      }
      __builtin_amdgcn_s_setprio(0);
    }

    // scorer epilogue: tanh(a+ab1) . aw2
    {
      float pr[4] = {0.f, 0.f, 0.f, 0.f};
#pragma unroll
      for (int q = 0; q < 2; ++q) {
        int j = js + q * 16 + lr;
        float bj = sAb1R[j], wj = sAw2R[j];
#pragma unroll
        for (int r = 0; r < 4; ++r) {
          float av = tanhf(acc2[q][r] + bj);
          pr[r] += av * wj;
        }
      }
#pragma unroll
      for (int msk = 1; msk <= 8; msk <<= 1)
#pragma unroll
        for (int r = 0; r < 4; ++r) pr[r] += __shfl_xor(pr[r], msk);
      if (lr == 0) {
#pragma unroll
        for (int r = 0; r < 4; ++r) sPart[mt * 16 + lg * 4 + r][w >> 1] = pr[r];
      }
    }
    barrier_lds();

    // ---------------- P4: masked softmax over n (first wave) ----------------
    if (t < 64) {
      float logit = -INFINITY;
      bool valid = false;
      if (t < 32) {
        float sv = sScal[1] + sPart[t][0] + sPart[t][1];
        valid = (mval != 0);
        logit = valid ? sv : -INFINITY;
      }
      float m = logit;
#pragma unroll
      for (int off = 32; off >= 1; off >>= 1) m = fmaxf(m, __shfl_xor(m, off));
      float e = (valid && m > -INFINITY) ? __expf(logit - m) : 0.0f;
      float ssum = e;
#pragma unroll
      for (int off = 32; off >= 1; off >>= 1) ssum += __shfl_xor(ssum, off);
      float at = (ssum > 0.0f) ? (e / ssum) : 0.0f;
      if (t < 32) {
        sAttn[t] = at;
        outAT[((size_t)b * LL + l) * NN + t] = at;
      }
    }
    barrier_lds();

    // ---------------- P5: fused[d] = sum_n attn[n] * per_msg[n][d] ----------------
    {
      int d = t;                            // 256 threads == D
      float f = 0.0f;
#pragma unroll
      for (int n = 0; n < NN; ++n) f += sAttn[n] * bf2f(sA[n * PA + d]);
      outF[(size_t)lb * DD + d] = f;
    }

    mval = mnext;
  }
}

extern "C" void kernel_launch(void* const* d_in, const int* in_sizes, int n_in,
                              void* d_out, int out_size, void* d_ws, size_t ws_size,
                              hipStream_t stream) {
  // Pre-pass: fp32 -> bf16 tiled weights into workspace (160 KB)
  wconv<<<dim3(320), dim3(256), 0, stream>>>(
      (const float*)d_in[3],            // gw1
      (const float*)d_in[7],            // aw1
      (unsigned short*)d_ws);

  dynfusion_kernel<<<dim3(NBLK), dim3(256), 0, stream>>>(
      (const float*)d_in[0],            // vert_feat
      (const float*)d_in[1],            // horiz_feat
      (const int*)d_in[2],              // mask_BNL bool (int32)
      (const float*)d_in[4],            // gb1
      (const float*)d_in[5],            // gw2
      (const float*)d_in[6],            // gb2
      (const float*)d_in[8],            // ab1
      (const float*)d_in[9],            // aw2
      (const float*)d_in[10],           // ab2
      (const unsigned short*)d_ws,      // bf16 tiled gw1/aw1
      (float*)d_out);
}

// Round 5
// 381.739 us; speedup vs baseline: 1.6570x; 1.6570x over previous
//
#include <hip/hip_runtime.h>
#include <hip/hip_bf16.h>
#include <math.h>

// Problem constants
#define LL 512
#define BB 8
#define NN 32
#define DD 256
#define GH 128
#define AH 64

#define PA 520     // sA pitch: [32 rows][512 k] bf16; row step 1040B -> 2-way bank alias (free)

typedef short short8 __attribute__((ext_vector_type(8)));   // 8 bf16 = 4 VGPRs (MFMA A/B frag)
typedef float f32x4  __attribute__((ext_vector_type(4)));   // MFMA C/D frag

__device__ __forceinline__ float bf2f(unsigned short u) {
  return __uint_as_float(((unsigned int)u) << 16);
}
__device__ __forceinline__ unsigned short f2bf(float f) {
  union { __hip_bfloat16 h; unsigned short u; } cv;
  cv.h = __float2bfloat16(f);
  return cv.u;
}

// Barrier that orders LDS only: does NOT drain vmcnt, so in-flight global
// stores (per_msg/attn/fused, never re-read in-kernel) and loads (register
// destinations, dependency-tracked) float across. All cross-wave
// communication in this kernel is through LDS -> lgkmcnt(0) is sufficient.
__device__ __forceinline__ void barrier_lds() {
  asm volatile("s_waitcnt lgkmcnt(0)" ::: "memory");
  __builtin_amdgcn_s_barrier();
  __builtin_amdgcn_sched_barrier(0);
}

// ---------------------------------------------------------------------------
// Pre-pass: gw1/aw1 fp32 -> bf16, tiled [k/32][j][32] so a wave's MFMA
// B-fragment load (lane (lr,lg) -> j=jt*16+lr, k=kb*32+lg*8) is one fully
// coalesced contiguous 1KB global_load_dwordx4 per fragment.
//   gw1t: ws[0      .. 65535] = gw1t[kb<16][j<128][ko<32]
//   aw1t: ws[65536 .. 81919]  = aw1t[kb< 8][j< 64][ko<32]
// ---------------------------------------------------------------------------
extern "C" __global__ void wconv(const float* __restrict__ gw1,
                                 const float* __restrict__ aw1,
                                 unsigned short* __restrict__ ws)
{
  int o = blockIdx.x * 256 + threadIdx.x;     // grid = 320*256 = 81920 exactly
  if (o < 65536) {
    int kb = o >> 12, r = o & 4095, j = r >> 5, ko = r & 31;
    ws[o] = f2bf(gw1[j * 512 + kb * 32 + ko]);
  } else {
    int o2 = o - 65536;
    int kb = o2 >> 11, j = (o2 >> 5) & 63, ko = o2 & 31;
    ws[o] = f2bf(aw1[j * 256 + kb * 32 + ko]);
  }
}

extern "C" __global__ __launch_bounds__(256, 4)
void dynfusion_kernel(const float* __restrict__ vert,
                      const float* __restrict__ horiz,
                      const int*   __restrict__ mask,   // [B][N][L] bool as int32
                      const float* __restrict__ gb1,    // [128]
                      const float* __restrict__ gw2,    // [1][128]
                      const float* __restrict__ gb2,    // [1]
                      const float* __restrict__ ab1,    // [64]
                      const float* __restrict__ aw2,    // [1][64]
                      const float* __restrict__ ab2,    // [1]
                      const unsigned short* __restrict__ ws,  // bf16 tiled weights
                      float* __restrict__ out)
{
  __shared__ __align__(16) unsigned short sA[NN * PA];   // 33,280 B (comb; pm overwrites k<256)
  __shared__ float sPart[NN][2];
  __shared__ float sGb1R[GH], sGw2R[GH];
  __shared__ float sAb1R[AH], sAw2R[AH];
  __shared__ float sGate[NN], sAttn[NN], sScal[2];

  const int t  = threadIdx.x;
  const int lb = blockIdx.x;            // l*8 + b
  const int l  = lb >> 3;
  const int b  = lb & 7;
  const size_t msgBase = (size_t)lb * NN * DD;

  const int lane = t & 63;
  const int w    = t >> 6;              // wave id 0..3
  const int lr   = lane & 15;           // row(A) / col(B,C) within 16-tile
  const int lg   = lane >> 4;           // k-group (8 consecutive k) / C row-group
  const int mt   = w & 1;               // M-tile (message group of 16)
  const int ns   = (w >> 1) << 6;       // GEMM1 j-strip base: 0 or 64
  const int js   = (w >> 1) << 5;       // GEMM2 j-strip base: 0 or 32
  const int aoff = (mt * 16 + lr) * PA; // A-frag row offset in sA

  const unsigned short* __restrict__ gw1t = ws;           // [16][128][32]
  const unsigned short* __restrict__ aw1t = ws + 65536;   // [8][64][32]

  float* __restrict__ outF  = out;                 // fused  [L,B,D]
  float* __restrict__ outPM = out + 1048576;       // per_msg[L,B,N,D]
  float* __restrict__ outAT = out + 34603008;      // attn   [B,L,N]

  // mask prefetch (used in P4 by wave 0)
  int mval = 0;
  if (t < NN) mval = mask[((size_t)b * NN + t) * LL + l];

  // ---------------- P0: stage small vectors + comb (row-major bf16) ----------------
  if (t < GH) { sGb1R[t] = gb1[t]; sGw2R[t] = gw2[t]; }
  if (t < AH) { sAb1R[t] = ab1[t]; sAw2R[t] = ab2 ? aw2[t] : aw2[t]; }
  if (t == 0) { sScal[0] = gb2[0]; sScal[1] = ab2[0]; }

  // Issue ALL 16 input loads first (16 outstanding HBM loads -> latency
  // amortized), then convert+stage. Live range of inr = P0 only (no spill).
  float4 inr[16];
#pragma unroll
  for (int i = 0; i < 16; ++i) {
    int idx4 = i * 256 + t;                 // 4096 float4 = 32 rows x 128 quads
    int n  = idx4 >> 7;
    int c4 = (idx4 & 127) << 2;             // wave-uniform vert/horiz split
    const float* src = (c4 < DD) ? (vert  + msgBase + n * DD + c4)
                                 : (horiz + msgBase + n * DD + (c4 - DD));
    inr[i] = *reinterpret_cast<const float4*>(src);
  }
#pragma unroll
  for (int i = 0; i < 16; ++i) {
    int idx4 = i * 256 + t;
    int n  = idx4 >> 7;
    int c4 = (idx4 & 127) << 2;
    ushort4 pk;
    pk.x = f2bf(inr[i].x); pk.y = f2bf(inr[i].y);
    pk.z = f2bf(inr[i].z); pk.w = f2bf(inr[i].w);
    *reinterpret_cast<ushort4*>(&sA[n * PA + c4]) = pk;
  }
  barrier_lds();

  // ---------------- P1: gate GEMM h[32][128] = comb[32][512] @ gw1^T (MFMA) ----------------
  // B-fragments stream from L2-resident tiled bf16 weights with a depth-3
  // rolling register buffer (12 frags in flight ~= L2 latency coverage).
  f32x4 acc1[4] = {};
  {
    const unsigned short* bgp = gw1t + (ns + lr) * 32 + lg * 8;  // + ks*4096 + nt*512
    short8 bfb[3][4];
#pragma unroll
    for (int pk = 0; pk < 3; ++pk)
#pragma unroll
      for (int nt = 0; nt < 4; ++nt)
        bfb[pk][nt] = *reinterpret_cast<const short8*>(bgp + pk * 4096 + nt * 512);
    __builtin_amdgcn_s_setprio(1);
#pragma unroll
    for (int ks = 0; ks < 16; ++ks) {
      short8 af = *reinterpret_cast<const short8*>(&sA[aoff + ks * 32 + lg * 8]);
#pragma unroll
      for (int nt = 0; nt < 4; ++nt)
        acc1[nt] = __builtin_amdgcn_mfma_f32_16x16x32_bf16(af, bfb[ks % 3][nt], acc1[nt], 0, 0, 0);
      if (ks + 3 < 16) {
#pragma unroll
        for (int nt = 0; nt < 4; ++nt)
          bfb[ks % 3][nt] = *reinterpret_cast<const short8*>(bgp + (ks + 3) * 4096 + nt * 512);
      }
    }
    __builtin_amdgcn_s_setprio(0);
  }

  // gate epilogue: relu(h+gb1) . gw2 ; lane holds rows mt*16+lg*4+r, col j=ns+nt*16+lr
  {
    float pr[4] = {0.f, 0.f, 0.f, 0.f};
#pragma unroll
    for (int nt = 0; nt < 4; ++nt) {
      int j = ns + nt * 16 + lr;
      float bj = sGb1R[j], wj = sGw2R[j];
#pragma unroll
      for (int r = 0; r < 4; ++r) {
        float hv = fmaxf(acc1[nt][r] + bj, 0.0f);
        pr[r] += hv * wj;
      }
    }
#pragma unroll
    for (int msk = 1; msk <= 8; msk <<= 1)
#pragma unroll
      for (int r = 0; r < 4; ++r) pr[r] += __shfl_xor(pr[r], msk);
    if (lr == 0) {
#pragma unroll
      for (int r = 0; r < 4; ++r) sPart[mt * 16 + lg * 4 + r][w >> 1] = pr[r];
    }
  }
  barrier_lds();
  if (t < NN) {
    float sv = sScal[0] + sPart[t][0] + sPart[t][1];
    sGate[t] = 1.0f / (1.0f + __expf(-sv));
  }
  barrier_lds();

  // ---------------- P2: per_msg = gate*vert + (1-gate)*horiz ----------------
  // overwrite k<256 half of sA with per_msg bf16; fp32 coalesced store to global
#pragma unroll
  for (int i = 0; i < 8; ++i) {
    int idx4 = i * 256 + t;                 // 2048 = 32 n x 64 quads
    int n  = idx4 >> 6;
    int d0 = (idx4 & 63) << 2;
    float g = sGate[n];
    ushort4 vq = *reinterpret_cast<const ushort4*>(&sA[n * PA + d0]);
    ushort4 hq = *reinterpret_cast<const ushort4*>(&sA[n * PA + DD + d0]);
    float4 prv;
    prv.x = bf2f(hq.x) + g * (bf2f(vq.x) - bf2f(hq.x));
    prv.y = bf2f(hq.y) + g * (bf2f(vq.y) - bf2f(hq.y));
    prv.z = bf2f(hq.z) + g * (bf2f(vq.z) - bf2f(hq.z));
    prv.w = bf2f(hq.w) + g * (bf2f(vq.w) - bf2f(hq.w));
    ushort4 pq;
    pq.x = f2bf(prv.x); pq.y = f2bf(prv.y); pq.z = f2bf(prv.z); pq.w = f2bf(prv.w);
    *reinterpret_cast<ushort4*>(&sA[n * PA + d0]) = pq;
    *reinterpret_cast<float4*>(outPM + msgBase + n * DD + d0) = prv;  // floats past barriers
  }
  barrier_lds();

  // ---------------- P3: scorer GEMM a[32][64] = pm[32][256] @ aw1^T (MFMA) ----------------
  f32x4 acc2[2] = {};
  {
    const unsigned short* bap = aw1t + (js + lr) * 32 + lg * 8;  // + ks*2048 + q*512
    short8 b2[8][2];                        // preload ALL 16 frags (64 VGPR, P3-local)
#pragma unroll
    for (int ks = 0; ks < 8; ++ks)
#pragma unroll
      for (int q = 0; q < 2; ++q)
        b2[ks][q] = *reinterpret_cast<const short8*>(bap + ks * 2048 + q * 512);
    __builtin_amdgcn_s_setprio(1);
#pragma unroll
    for (int ks = 0; ks < 8; ++ks) {
      short8 af = *reinterpret_cast<const short8*>(&sA[aoff + ks * 32 + lg * 8]);
#pragma unroll
      for (int q = 0; q < 2; ++q)
        acc2[q] = __builtin_amdgcn_mfma_f32_16x16x32_bf16(af, b2[ks][q], acc2[q], 0, 0, 0);
    }
    __builtin_amdgcn_s_setprio(0);
  }

  // scorer epilogue: tanh(a+ab1) . aw2
  {
    float pr[4] = {0.f, 0.f, 0.f, 0.f};
#pragma unroll
    for (int q = 0; q < 2; ++q) {
      int j = js + q * 16 + lr;
      float bj = sAb1R[j], wj = sAw2R[j];
#pragma unroll
      for (int r = 0; r < 4; ++r) {
        float av = tanhf(acc2[q][r] + bj);
        pr[r] += av * wj;
      }
    }
#pragma unroll
    for (int msk = 1; msk <= 8; msk <<= 1)
#pragma unroll
      for (int r = 0; r < 4; ++r) pr[r] += __shfl_xor(pr[r], msk);
    if (lr == 0) {
#pragma unroll
      for (int r = 0; r < 4; ++r) sPart[mt * 16 + lg * 4 + r][w >> 1] = pr[r];
    }
  }
  barrier_lds();

  // ---------------- P4: masked softmax over n (first wave) ----------------
  if (t < 64) {
    float logit = -INFINITY;
    bool valid = false;
    if (t < 32) {
      float sv = sScal[1] + sPart[t][0] + sPart[t][1];
      valid = (mval != 0);
      logit = valid ? sv : -INFINITY;
    }
    float m = logit;
#pragma unroll
    for (int off = 32; off >= 1; off >>= 1) m = fmaxf(m, __shfl_xor(m, off));
    float e = (valid && m > -INFINITY) ? __expf(logit - m) : 0.0f;
    float ssum = e;
#pragma unroll
    for (int off = 32; off >= 1; off >>= 1) ssum += __shfl_xor(ssum, off);
    float at = (ssum > 0.0f) ? (e / ssum) : 0.0f;
    if (t < 32) {
      sAttn[t] = at;
      outAT[((size_t)b * LL + l) * NN + t] = at;
    }
  }
  barrier_lds();

  // ---------------- P5: fused[d] = sum_n attn[n] * per_msg[n][d] ----------------
  {
    int d = t;                              // 256 threads == D
    float f = 0.0f;
#pragma unroll
    for (int n = 0; n < NN; ++n) f += sAttn[n] * bf2f(sA[n * PA + d]);
    outF[(size_t)lb * DD + d] = f;
  }
}

extern "C" void kernel_launch(void* const* d_in, const int* in_sizes, int n_in,
                              void* d_out, int out_size, void* d_ws, size_t ws_size,
                              hipStream_t stream) {
  // Pre-pass: fp32 -> bf16 tiled weights into workspace (160 KB)
  wconv<<<dim3(320), dim3(256), 0, stream>>>(
      (const float*)d_in[3],            // gw1
      (const float*)d_in[7],            // aw1
      (unsigned short*)d_ws);

  dynfusion_kernel<<<dim3(LL * BB), dim3(256), 0, stream>>>(
      (const float*)d_in[0],            // vert_feat
      (const float*)d_in[1],            // horiz_feat
      (const int*)d_in[2],              // mask_BNL bool (int32)
      (const float*)d_in[4],            // gb1
      (const float*)d_in[5],            // gw2
      (const float*)d_in[6],            // gb2
      (const float*)d_in[8],            // ab1
      (const float*)d_in[9],            // aw2
      (const float*)d_in[10],           // ab2
      (const unsigned short*)d_ws,      // bf16 tiled gw1/aw1
      (float*)d_out);
}